// Round 2
// baseline (214.385 us; speedup 1.0000x reference)
//
#include <hip/hip_runtime.h>

#define DEV static __device__ __forceinline__

typedef __bf16 bf16x8 __attribute__((ext_vector_type(8)));
typedef __bf16 bf16x4 __attribute__((ext_vector_type(4)));
typedef float f32x4 __attribute__((ext_vector_type(4)));
typedef float f32x16 __attribute__((ext_vector_type(16)));
typedef unsigned int uint4v __attribute__((ext_vector_type(4)));
typedef unsigned short ushort4v __attribute__((ext_vector_type(4)));
using u16 = unsigned short;

#define NN 2048
#define DIMD 1024

DEV u16 f2bf(float f) {  // RNE via hardware cvt
    __bf16 b = (__bf16)f;
    return __builtin_bit_cast(u16, b);
}
DEV float bf2f(u16 s) {
    unsigned u = ((unsigned)s) << 16;
    return __builtin_bit_cast(float, u);
}
DEV bf16x8 load16(const u16* p) { return __builtin_bit_cast(bf16x8, *(const uint4v*)p); }
DEV f32x4 mfma16(bf16x8 a, bf16x8 b, f32x4 c) {
    return __builtin_amdgcn_mfma_f32_16x16x32_bf16(a, b, c, 0, 0, 0);
}
DEV f32x16 mfma32(bf16x8 a, bf16x8 b, f32x16 c) {
    return __builtin_amdgcn_mfma_f32_32x32x16_bf16(a, b, c, 0, 0, 0);
}
DEV float wredsum(float v) {
#pragma unroll
    for (int o = 32; o; o >>= 1) v += __shfl_xor(v, o);
    return v;
}
// async global->LDS, 16B per lane; lds base must be wave-uniform
DEV void gl_lds16(const u16* g, u16* l) {
    __builtin_amdgcn_global_load_lds((const __attribute__((address_space(1))) void*)g,
                                     (__attribute__((address_space(3))) void*)l, 16, 0, 0);
}

// ---------------- prep kernels ----------------

__global__ __launch_bounds__(256) void k_pack_x(const float* __restrict__ x,
                                                u16* __restrict__ xb, int n4) {
    int i = blockIdx.x * 256 + threadIdx.x;
    if (i >= n4) return;
    float4 v = ((const float4*)x)[i];
    ushort4v o;
    o[0] = f2bf(v.x); o[1] = f2bf(v.y); o[2] = f2bf(v.z); o[3] = f2bf(v.w);
    *(ushort4v*)(xb + (size_t)i * 4) = o;
}

// dst[n][k] = src[k][n], 1024x1024, fp32 -> bf16
__global__ __launch_bounds__(256) void k_transpose_w(const float* __restrict__ s0,
                                                     const float* __restrict__ s1,
                                                     const float* __restrict__ s2,
                                                     const float* __restrict__ s3,
                                                     u16* __restrict__ wqkv_t,
                                                     u16* __restrict__ wo_t) {
    __shared__ float tile[32][33];
    int z = blockIdx.z;
    const float* src = (z == 0) ? s0 : (z == 1) ? s1 : (z == 2) ? s2 : s3;
    u16* dst = (z < 3) ? (wqkv_t + (size_t)z * 1024 * 1024) : wo_t;
    int tx = threadIdx.x & 31, ty = threadIdx.x >> 5;  // ty 0..7
    int kb = blockIdx.y * 32, nb = blockIdx.x * 32;
#pragma unroll
    for (int j = 0; j < 4; ++j)
        tile[ty + 8 * j][tx] = src[(size_t)(kb + ty + 8 * j) * 1024 + nb + tx];
    __syncthreads();
#pragma unroll
    for (int j = 0; j < 4; ++j)
        dst[(size_t)(nb + ty + 8 * j) * 1024 + kb + tx] = f2bf(tile[tx][ty + 8 * j]);
}

__global__ __launch_bounds__(256) void k_pack_bias(const float* __restrict__ bq,
                                                   const float* __restrict__ bk,
                                                   const float* __restrict__ bv,
                                                   float* __restrict__ bqkv) {
    int i = blockIdx.x * 256 + threadIdx.x;
    if (i >= 3072) return;
    bqkv[i] = (i < 1024) ? bq[i] : (i < 2048) ? bk[i - 1024] : bv[i - 2048];
}

// ---------------- GEMM: C[m][n] = A[m][K] * Bt[n][K]^T, K=1024 ----------------
// m97 structure: global_load_lds width-16 into linear LDS, 128x128 tile, BK=32.
// MODE 0: out bf16 = acc + bias[n]          (ldc = Ncols)
// MODE 1: out fp32 = (acc + bias[n])*gamma[n]
template <int MODE>
__global__ __launch_bounds__(256) void k_gemm(const u16* __restrict__ A,
                                              const u16* __restrict__ Bt,
                                              const float* __restrict__ bias,
                                              const float* __restrict__ gamma,
                                              void* __restrict__ out, int ldc) {
    __shared__ u16 As[128 * 32];  // linear: row stride 32 elems (64B)
    __shared__ u16 Bs[128 * 32];
    const int K = 1024;
    const int m0 = blockIdx.x * 128, n0 = blockIdx.y * 128;
    const int tid = threadIdx.x;
    const int lane = tid & 63, w = tid >> 6;
    const int wr = w >> 1, wc = w & 1;
    const int li = lane & 15, g = lane >> 4;

    f32x4 acc[4][4] = {};

    // staging: wave w covers rows w*16 + lane/4 (and +64), 16B per lane
    const u16* gA = A + (size_t)(m0 + w * 16 + (lane >> 2)) * K + (lane & 3) * 8;
    const u16* gB = Bt + (size_t)(n0 + w * 16 + (lane >> 2)) * K + (lane & 3) * 8;
    u16* lA = &As[(w * 16) * 32];  // wave-uniform; HW adds lane*16B
    u16* lB = &Bs[(w * 16) * 32];

    for (int k0 = 0; k0 < K; k0 += 32) {
        __syncthreads();  // all reads of previous tile done
        gl_lds16(gA + k0, lA);
        gl_lds16(gA + (size_t)64 * K + k0, lA + 64 * 32);
        gl_lds16(gB + k0, lB);
        gl_lds16(gB + (size_t)64 * K + k0, lB + 64 * 32);
        asm volatile("s_waitcnt vmcnt(0)" ::: "memory");
        __syncthreads();  // tile visible
        bf16x8 af[4], bfv[4];
#pragma unroll
        for (int mi = 0; mi < 4; ++mi)
            af[mi] = load16(&As[(wr * 64 + mi * 16 + li) * 32 + g * 8]);
#pragma unroll
        for (int ni = 0; ni < 4; ++ni)
            bfv[ni] = load16(&Bs[(wc * 64 + ni * 16 + li) * 32 + g * 8]);
#pragma unroll
        for (int mi = 0; mi < 4; ++mi)
#pragma unroll
            for (int ni = 0; ni < 4; ++ni)
                acc[mi][ni] = mfma16(af[mi], bfv[ni], acc[mi][ni]);
    }

#pragma unroll
    for (int mi = 0; mi < 4; ++mi) {
        int row = m0 + wr * 64 + mi * 16 + 4 * g;  // C/D: row = 4*(lane>>4)+r
#pragma unroll
        for (int ni = 0; ni < 4; ++ni) {
            int col = n0 + wc * 64 + ni * 16 + li;  // C/D: col = lane&15
            float bv_ = bias[col];
            f32x4 v = acc[mi][ni];
            if (MODE == 0) {
                u16* o = (u16*)out;
#pragma unroll
                for (int r = 0; r < 4; ++r)
                    o[(size_t)(row + r) * ldc + col] = f2bf(v[r] + bv_);
            } else {
                float gv = gamma[col];
                float* o = (float*)out;
#pragma unroll
                for (int r = 0; r < 4; ++r)
                    o[(size_t)(row + r) * ldc + col] = (v[r] + bv_) * gv;
            }
        }
    }
}

// ---------------- LayerNorm(q,k over D=64) + repack, V transpose ----------------
// qkv: [4096][3072] bf16 (q|k|v). Out: Qn,Kn [bh][n][64] bf16; Vt [bh][64][N] bf16.
__global__ __launch_bounds__(256) void k_ln_repack(const u16* __restrict__ qkv,
                                                   const float* __restrict__ qs,
                                                   const float* __restrict__ qb,
                                                   const float* __restrict__ ks,
                                                   const float* __restrict__ kb,
                                                   u16* __restrict__ Qn,
                                                   u16* __restrict__ Kn,
                                                   u16* __restrict__ Vt) {
    __shared__ u16 vtile[64][72];
    const int bh = blockIdx.y, b = bh >> 4, h = bh & 15;
    const int n0 = blockIdx.x * 64;
    const int tid = threadIdx.x;
    const int wv = tid >> 6, lane = tid & 63;  // lane == d
    const float qsv = qs[lane], qbv = qb[lane], ksv = ks[lane], kbv = kb[lane];
    for (int rr = 0; rr < 16; ++rr) {
        const int nl = wv * 16 + rr;
        const int n = n0 + nl;
        const size_t base = (size_t)(b * NN + n) * 3072 + h * 64 + lane;
        float qf = bf2f(qkv[base]);
        float kf = bf2f(qkv[base + 1024]);
        float vf = bf2f(qkv[base + 2048]);
        float mq = wredsum(qf) * (1.0f / 64.0f);
        float dq = qf - mq;
        float vq = wredsum(dq * dq) * (1.0f / 64.0f);
        Qn[((size_t)bh * NN + n) * 64 + lane] = f2bf(dq * rsqrtf(vq + 1e-6f) * qsv + qbv);
        float mk = wredsum(kf) * (1.0f / 64.0f);
        float dk = kf - mk;
        float vk = wredsum(dk * dk) * (1.0f / 64.0f);
        Kn[((size_t)bh * NN + n) * 64 + lane] = f2bf(dk * rsqrtf(vk + 1e-6f) * ksv + kbv);
        vtile[nl][lane] = f2bf(vf);
    }
    __syncthreads();
    const int d = tid >> 2, c = tid & 3;
    alignas(16) u16 tmp[16];
#pragma unroll
    for (int k2 = 0; k2 < 16; ++k2) tmp[k2] = vtile[16 * c + k2][d];
    const size_t vbase = ((size_t)bh * 64 + d) * NN + n0 + 16 * c;
    *(uint4v*)(Vt + vbase) = *(const uint4v*)&tmp[0];
    *(uint4v*)(Vt + vbase + 8) = *(const uint4v*)&tmp[8];
}

// ---------------- fused sigmoid attention (32x32 MFMA) ----------------
// Per block: one (b,h), 64 query rows, j-step 64. 4 waves; wave w owns
// quadrant (wj=w>>1, wi=w&1) of S^T = K.Q^T, and (wd=w>>1, wi) of O^T = Vt.P^T.
// P routed via LDS layout [frag J>>3][i 0..63][J&7] bf16 (8KB):
//   writer: 4x ds_write_b64, reader: 4x conflict-free ds_read_b128.
__global__ __launch_bounds__(256) void k_attn(const u16* __restrict__ Qn,
                                              const u16* __restrict__ Kn,
                                              const u16* __restrict__ Vt,
                                              const float* __restrict__ ib,
                                              u16* __restrict__ attn_out) {
    __shared__ __bf16 P[8 * 64 * 8];  // 8KB
    const int bh = blockIdx.y, b = bh >> 4, h = bh & 15;
    const int i0 = blockIdx.x * 64;
    const int tid = threadIdx.x;
    const int w = tid >> 6, lane = tid & 63;
    const int l32 = lane & 31, hi = lane >> 5;
    const int wj = w >> 1, wi = w & 1;  // wd == wj for PV
    const float nbias = -ib[0];
    const u16* Qb = Qn + (size_t)bh * NN * 64;
    const u16* Kb = Kn + (size_t)bh * NN * 64;
    const u16* Vb = Vt + (size_t)bh * 64 * NN;

    // Q fragments (B-operand): Q[i0+32*wi+l32][16s+8hi .. +8], hoisted
    bf16x8 qf[4];
#pragma unroll
    for (int s = 0; s < 4; ++s)
        qf[s] = load16(Qb + (size_t)(i0 + 32 * wi + l32) * 64 + 16 * s + 8 * hi);

    f32x16 accO = {};
    const int widx = ((4 * wj) * 64 + (32 * wi + l32)) * 8 + 4 * hi;  // + q*512
    const int ridx = (hi * 64 + 32 * wi + l32) * 8;                   // + s*1024

    for (int j0 = 0; j0 < NN; j0 += 64) {
        // QK^T: S^T quadrant [32j][32i], K=64 as 4 k-slices
        f32x16 sa = {};
#pragma unroll
        for (int s = 0; s < 4; ++s) {
            bf16x8 kf = load16(Kb + (size_t)(j0 + 32 * wj + l32) * 64 + 16 * s + 8 * hi);
            sa = mfma32(kf, qf[s], sa);
        }
        // V fragments for this j-tile: issue early, consumed after barrier
        bf16x8 vf[4];
#pragma unroll
        for (int s = 0; s < 4; ++s)
            vf[s] = load16(Vb + (size_t)(32 * wj + l32) * NN + j0 + 16 * s + 8 * hi);
        // sigmoid -> bf16
        bf16x4 pw[4];
#pragma unroll
        for (int r = 0; r < 16; ++r) {
            float e = __expf(nbias - sa[r]);
            pw[r >> 2][r & 3] = (__bf16)__builtin_amdgcn_rcpf(1.0f + e);
        }
        __syncthreads();  // previous iteration's P reads complete
#pragma unroll
        for (int q = 0; q < 4; ++q)
            *(bf16x4*)&P[widx + q * 512] = pw[q];
        __syncthreads();  // P ready
        // PV: O^T quadrant [32d][32i] += Vt[32d][j] * P^T[j][32i]
#pragma unroll
        for (int s = 0; s < 4; ++s) {
            bf16x8 pf = *(const bf16x8*)&P[ridx + s * 1024];
            accO = mfma32(vf[s], pf, accO);
        }
    }

    // epilogue: O^T C/D -> attn_out[(b*N+i)][h*64+d] bf16
    const int i = i0 + 32 * wi + l32;
#pragma unroll
    for (int q = 0; q < 4; ++q) {
        int d = 32 * wj + 8 * q + 4 * hi;
        bf16x4 o4;
#pragma unroll
        for (int r = 0; r < 4; ++r) o4[r] = (__bf16)accO[4 * q + r];
        *(bf16x4*)&attn_out[(size_t)(b * NN + i) * 1024 + h * 64 + d] = o4;
    }
}

// ---------------- launch ----------------

extern "C" void kernel_launch(void* const* d_in, const int* in_sizes, int n_in,
                              void* d_out, int out_size, void* d_ws, size_t ws_size,
                              hipStream_t stream) {
    (void)in_sizes; (void)n_in; (void)out_size; (void)ws_size;
    const float* x     = (const float*)d_in[0];
    const float* Wq    = (const float*)d_in[1];
    const float* bq    = (const float*)d_in[2];
    const float* Wk    = (const float*)d_in[3];
    const float* bk    = (const float*)d_in[4];
    const float* Wv    = (const float*)d_in[5];
    const float* bv    = (const float*)d_in[6];
    const float* qn_s  = (const float*)d_in[7];
    const float* qn_b  = (const float*)d_in[8];
    const float* kn_s  = (const float*)d_in[9];
    const float* kn_b  = (const float*)d_in[10];
    const float* ib    = (const float*)d_in[11];
    const float* Wo    = (const float*)d_in[12];
    const float* bo    = (const float*)d_in[13];
    const float* gamma = (const float*)d_in[14];
    float* out = (float*)d_out;

    char* ws = (char*)d_ws;
    size_t off = 0;
    auto alloc = [&](size_t bytes) -> void* {
        void* p = ws + off;
        off += (bytes + 255) & ~(size_t)255;
        return p;
    };
    u16* xb       = (u16*)alloc((size_t)4096 * 1024 * 2);   // x bf16
    u16* wqkv_t   = (u16*)alloc((size_t)3072 * 1024 * 2);   // [n][k]
    u16* wo_t     = (u16*)alloc((size_t)1024 * 1024 * 2);
    float* bqkv   = (float*)alloc((size_t)3072 * 4);
    u16* qkv_raw  = (u16*)alloc((size_t)4096 * 3072 * 2);   // q|k|v rows
    u16* Qn       = (u16*)alloc((size_t)32 * 2048 * 64 * 2);
    u16* Kn       = (u16*)alloc((size_t)32 * 2048 * 64 * 2);
    u16* Vtp      = (u16*)alloc((size_t)32 * 64 * 2048 * 2);
    u16* attn_out = (u16*)alloc((size_t)4096 * 1024 * 2);

    k_pack_x<<<4096, 256, 0, stream>>>(x, xb, 1048576);
    k_transpose_w<<<dim3(32, 32, 4), 256, 0, stream>>>(Wq, Wk, Wv, Wo, wqkv_t, wo_t);
    k_pack_bias<<<12, 256, 0, stream>>>(bq, bk, bv, bqkv);
    k_gemm<0><<<dim3(32, 24), 256, 0, stream>>>(xb, wqkv_t, bqkv, nullptr, qkv_raw, 3072);
    k_ln_repack<<<dim3(32, 32), 256, 0, stream>>>(qkv_raw, qn_s, qn_b, kn_s, kn_b, Qn, Kn, Vtp);
    k_attn<<<dim3(32, 32), 256, 0, stream>>>(Qn, Kn, Vtp, ib, attn_out);
    k_gemm<1><<<dim3(32, 8), 256, 0, stream>>>(attn_out, wo_t, bo, gamma, out, 1024);
}

// Round 3
// 212.660 us; speedup vs baseline: 1.0081x; 1.0081x over previous
//
#include <hip/hip_runtime.h>

#define DEV static __device__ __forceinline__

typedef __bf16 bf16x8 __attribute__((ext_vector_type(8)));
typedef __bf16 bf16x4 __attribute__((ext_vector_type(4)));
typedef float f32x4 __attribute__((ext_vector_type(4)));
typedef float f32x16 __attribute__((ext_vector_type(16)));
typedef unsigned int uint4v __attribute__((ext_vector_type(4)));
typedef unsigned short ushort4v __attribute__((ext_vector_type(4)));
using u16 = unsigned short;

#define NN 2048
#define DIMD 1024

DEV u16 f2bf(float f) {  // RNE via hardware cvt
    __bf16 b = (__bf16)f;
    return __builtin_bit_cast(u16, b);
}
DEV float bf2f(u16 s) {
    unsigned u = ((unsigned)s) << 16;
    return __builtin_bit_cast(float, u);
}
DEV bf16x8 load16(const u16* p) { return __builtin_bit_cast(bf16x8, *(const uint4v*)p); }
DEV f32x4 mfma16(bf16x8 a, bf16x8 b, f32x4 c) {
    return __builtin_amdgcn_mfma_f32_16x16x32_bf16(a, b, c, 0, 0, 0);
}
DEV f32x16 mfma32(bf16x8 a, bf16x8 b, f32x16 c) {
    return __builtin_amdgcn_mfma_f32_32x32x16_bf16(a, b, c, 0, 0, 0);
}
DEV float wredsum(float v) {
#pragma unroll
    for (int o = 32; o; o >>= 1) v += __shfl_xor(v, o);
    return v;
}
// async global->LDS, 16B per lane; lds base must be wave-uniform
DEV void gl_lds16(const u16* g, u16* l) {
    __builtin_amdgcn_global_load_lds((const __attribute__((address_space(1))) void*)g,
                                     (__attribute__((address_space(3))) void*)l, 16, 0, 0);
}

// ---------------- prep kernels ----------------

__global__ __launch_bounds__(256) void k_pack_x(const float* __restrict__ x,
                                                u16* __restrict__ xb, int n4) {
    int i = blockIdx.x * 256 + threadIdx.x;
    if (i >= n4) return;
    float4 v = ((const float4*)x)[i];
    ushort4v o;
    o[0] = f2bf(v.x); o[1] = f2bf(v.y); o[2] = f2bf(v.z); o[3] = f2bf(v.w);
    *(ushort4v*)(xb + (size_t)i * 4) = o;
}

// dst[n][k] = src[k][n], 1024x1024, fp32 -> bf16
__global__ __launch_bounds__(256) void k_transpose_w(const float* __restrict__ s0,
                                                     const float* __restrict__ s1,
                                                     const float* __restrict__ s2,
                                                     const float* __restrict__ s3,
                                                     u16* __restrict__ wqkv_t,
                                                     u16* __restrict__ wo_t) {
    __shared__ float tile[32][33];
    int z = blockIdx.z;
    const float* src = (z == 0) ? s0 : (z == 1) ? s1 : (z == 2) ? s2 : s3;
    u16* dst = (z < 3) ? (wqkv_t + (size_t)z * 1024 * 1024) : wo_t;
    int tx = threadIdx.x & 31, ty = threadIdx.x >> 5;  // ty 0..7
    int kb = blockIdx.y * 32, nb = blockIdx.x * 32;
#pragma unroll
    for (int j = 0; j < 4; ++j)
        tile[ty + 8 * j][tx] = src[(size_t)(kb + ty + 8 * j) * 1024 + nb + tx];
    __syncthreads();
#pragma unroll
    for (int j = 0; j < 4; ++j)
        dst[(size_t)(nb + ty + 8 * j) * 1024 + kb + tx] = f2bf(tile[tx][ty + 8 * j]);
}

__global__ __launch_bounds__(256) void k_pack_bias(const float* __restrict__ bq,
                                                   const float* __restrict__ bk,
                                                   const float* __restrict__ bv,
                                                   float* __restrict__ bqkv) {
    int i = blockIdx.x * 256 + threadIdx.x;
    if (i >= 3072) return;
    bqkv[i] = (i < 1024) ? bq[i] : (i < 2048) ? bk[i - 1024] : bv[i - 2048];
}

// ---------------- GEMM: C[m][n] = A[m][K] * Bt[n][K]^T, K=1024 ----------------
// m97 structure: global_load_lds width-16 into linear LDS, 128x128 tile, BK=32.
// MODE 0: out bf16 = acc + bias[n]          (ldc = Ncols)
// MODE 1: out fp32 = (acc + bias[n])*gamma[n]
template <int MODE>
__global__ __launch_bounds__(256) void k_gemm(const u16* __restrict__ A,
                                              const u16* __restrict__ Bt,
                                              const float* __restrict__ bias,
                                              const float* __restrict__ gamma,
                                              void* __restrict__ out, int ldc) {
    __shared__ u16 As[128 * 32];  // linear: row stride 32 elems (64B)
    __shared__ u16 Bs[128 * 32];
    const int K = 1024;
    const int m0 = blockIdx.x * 128, n0 = blockIdx.y * 128;
    const int tid = threadIdx.x;
    const int lane = tid & 63, w = tid >> 6;
    const int wr = w >> 1, wc = w & 1;
    const int li = lane & 15, g = lane >> 4;

    f32x4 acc[4][4] = {};

    // staging: wave w covers rows w*16 + lane/4 (and +64), 16B per lane
    const u16* gA = A + (size_t)(m0 + w * 16 + (lane >> 2)) * K + (lane & 3) * 8;
    const u16* gB = Bt + (size_t)(n0 + w * 16 + (lane >> 2)) * K + (lane & 3) * 8;
    u16* lA = &As[(w * 16) * 32];  // wave-uniform; HW adds lane*16B
    u16* lB = &Bs[(w * 16) * 32];

    for (int k0 = 0; k0 < K; k0 += 32) {
        __syncthreads();  // all reads of previous tile done
        gl_lds16(gA + k0, lA);
        gl_lds16(gA + (size_t)64 * K + k0, lA + 64 * 32);
        gl_lds16(gB + k0, lB);
        gl_lds16(gB + (size_t)64 * K + k0, lB + 64 * 32);
        asm volatile("s_waitcnt vmcnt(0)" ::: "memory");
        __syncthreads();  // tile visible
        bf16x8 af[4], bfv[4];
#pragma unroll
        for (int mi = 0; mi < 4; ++mi)
            af[mi] = load16(&As[(wr * 64 + mi * 16 + li) * 32 + g * 8]);
#pragma unroll
        for (int ni = 0; ni < 4; ++ni)
            bfv[ni] = load16(&Bs[(wc * 64 + ni * 16 + li) * 32 + g * 8]);
#pragma unroll
        for (int mi = 0; mi < 4; ++mi)
#pragma unroll
            for (int ni = 0; ni < 4; ++ni)
                acc[mi][ni] = mfma16(af[mi], bfv[ni], acc[mi][ni]);
    }

#pragma unroll
    for (int mi = 0; mi < 4; ++mi) {
        int row = m0 + wr * 64 + mi * 16 + 4 * g;  // C/D: row = 4*(lane>>4)+r
#pragma unroll
        for (int ni = 0; ni < 4; ++ni) {
            int col = n0 + wc * 64 + ni * 16 + li;  // C/D: col = lane&15
            float bv_ = bias[col];
            f32x4 v = acc[mi][ni];
            if (MODE == 0) {
                u16* o = (u16*)out;
#pragma unroll
                for (int r = 0; r < 4; ++r)
                    o[(size_t)(row + r) * ldc + col] = f2bf(v[r] + bv_);
            } else {
                float gv = gamma[col];
                float* o = (float*)out;
#pragma unroll
                for (int r = 0; r < 4; ++r)
                    o[(size_t)(row + r) * ldc + col] = (v[r] + bv_) * gv;
            }
        }
    }
}

// ---------------- LayerNorm(q,k over D=64) + repack, V transpose ----------------
// qkv: [4096][3072] bf16 (q|k|v). Out: Qn,Kn [bh][n][64] bf16; Vt [bh][64][N] bf16.
__global__ __launch_bounds__(256) void k_ln_repack(const u16* __restrict__ qkv,
                                                   const float* __restrict__ qs,
                                                   const float* __restrict__ qb,
                                                   const float* __restrict__ ks,
                                                   const float* __restrict__ kb,
                                                   u16* __restrict__ Qn,
                                                   u16* __restrict__ Kn,
                                                   u16* __restrict__ Vt) {
    __shared__ u16 vtile[64][72];
    const int bh = blockIdx.y, b = bh >> 4, h = bh & 15;
    const int n0 = blockIdx.x * 64;
    const int tid = threadIdx.x;
    const int wv = tid >> 6, lane = tid & 63;  // lane == d
    const float qsv = qs[lane], qbv = qb[lane], ksv = ks[lane], kbv = kb[lane];
    for (int rr = 0; rr < 16; ++rr) {
        const int nl = wv * 16 + rr;
        const int n = n0 + nl;
        const size_t base = (size_t)(b * NN + n) * 3072 + h * 64 + lane;
        float qf = bf2f(qkv[base]);
        float kf = bf2f(qkv[base + 1024]);
        float vf = bf2f(qkv[base + 2048]);
        float mq = wredsum(qf) * (1.0f / 64.0f);
        float dq = qf - mq;
        float vq = wredsum(dq * dq) * (1.0f / 64.0f);
        Qn[((size_t)bh * NN + n) * 64 + lane] = f2bf(dq * rsqrtf(vq + 1e-6f) * qsv + qbv);
        float mk = wredsum(kf) * (1.0f / 64.0f);
        float dk = kf - mk;
        float vk = wredsum(dk * dk) * (1.0f / 64.0f);
        Kn[((size_t)bh * NN + n) * 64 + lane] = f2bf(dk * rsqrtf(vk + 1e-6f) * ksv + kbv);
        vtile[nl][lane] = f2bf(vf);
    }
    __syncthreads();
    const int d = tid >> 2, c = tid & 3;
    alignas(16) u16 tmp[16];
#pragma unroll
    for (int k2 = 0; k2 < 16; ++k2) tmp[k2] = vtile[16 * c + k2][d];
    const size_t vbase = ((size_t)bh * 64 + d) * NN + n0 + 16 * c;
    *(uint4v*)(Vt + vbase) = *(const uint4v*)&tmp[0];
    *(uint4v*)(Vt + vbase + 8) = *(const uint4v*)&tmp[8];
}

// ---------------- fused sigmoid attention v3 ----------------
// Barrier-free j-loop. 4 waves/block: wave (wi=w&1, jh=w>>1) owns 32 queries
// (i0 = iblk*64 + wi*32) and j-half jh (1024 keys). Per 32-key step:
//   S^T = K.Q^T (4x mfma32), sigmoid in-register, P->bf16 B-fragments via
//   v_cvt_pk_bf16_f32 + v_permlane32_swap_b32 (T12), O^T += V^T.P^T (4x mfma32).
// j-halves combined once at the end through LDS (pad-65, <=2-way banks).
// XCD-bijective swizzle: 4 bh per XCD -> K/V (2MB) L2-resident.
__global__ __launch_bounds__(256) void k_attn(const u16* __restrict__ Qn,
                                              const u16* __restrict__ Kn,
                                              const u16* __restrict__ Vt,
                                              const float* __restrict__ ib,
                                              u16* __restrict__ attn_out) {
    __shared__ float red[64][65];
    const int bid = blockIdx.x;
    const int xcd = bid & 7, idx = bid >> 3;      // 1024 blocks: 128 per XCD
    const int bh = xcd * 4 + (idx >> 5);          // 4 bh per XCD
    const int iblk = idx & 31;
    const int b = bh >> 4, h = bh & 15;
    const int tid = threadIdx.x;
    const int w = tid >> 6, lane = tid & 63;
    const int l32 = lane & 31, hi = lane >> 5;
    const int wi = w & 1, jh = w >> 1;
    const int i0 = iblk * 64 + wi * 32;
    const float nbias = -ib[0];
    const u16* Qb = Qn + (size_t)bh * NN * 64;
    const u16* Kb = Kn + (size_t)bh * NN * 64 + (size_t)(jh * 1024) * 64;
    const u16* Vb = Vt + (size_t)bh * 64 * NN + jh * 1024;

    // Q fragments (B-operand of S^T): Q[i0+l32][16s+8hi..+8], hoisted
    bf16x8 qf[4];
#pragma unroll
    for (int s = 0; s < 4; ++s)
        qf[s] = load16(Qb + (size_t)(i0 + l32) * 64 + 16 * s + 8 * hi);

    f32x16 accO[2] = {f32x16{}, f32x16{}};

    for (int j0 = 0; j0 < 1024; j0 += 32) {
        // QK^T: S^T[32j][32i], A=K (row=j), B=Q^T (col=i), K=64 in 4 slices
        bf16x8 kf[4];
#pragma unroll
        for (int s = 0; s < 4; ++s)
            kf[s] = load16(Kb + (size_t)(j0 + l32) * 64 + 16 * s + 8 * hi);
        f32x16 sa = {};
#pragma unroll
        for (int s = 0; s < 4; ++s) sa = mfma32(kf[s], qf[s], sa);
        // V fragments: A[row=d][k=j], two d-blocks x two j-slices
        bf16x8 vf[2][2];
#pragma unroll
        for (int db = 0; db < 2; ++db)
#pragma unroll
            for (int js = 0; js < 2; ++js)
                vf[db][js] =
                    load16(Vb + (size_t)(db * 32 + l32) * NN + j0 + js * 16 + 8 * hi);
        // sigmoid (lane holds j = (r&3)+8(r>>2)+4hi, col i = l32)
        float p[16];
#pragma unroll
        for (int r = 0; r < 16; ++r)
            p[r] = __builtin_amdgcn_rcpf(1.0f + __expf(nbias - sa[r]));
        // pack to bf16 pairs, then swap lane<32/lane>=32 halves (T12):
        // after swap(w0,w2),swap(w1,w3): words already in B-fragment order.
        unsigned wd[8];
#pragma unroll
        for (int t = 0; t < 8; ++t) {
            unsigned r_;
            asm("v_cvt_pk_bf16_f32 %0, %1, %2" : "=v"(r_) : "v"(p[2 * t]), "v"(p[2 * t + 1]));
            wd[t] = r_;
        }
        asm("v_permlane32_swap_b32 %0, %1" : "+v"(wd[0]), "+v"(wd[2]));
        asm("v_permlane32_swap_b32 %0, %1" : "+v"(wd[1]), "+v"(wd[3]));
        asm("v_permlane32_swap_b32 %0, %1" : "+v"(wd[4]), "+v"(wd[6]));
        asm("v_permlane32_swap_b32 %0, %1" : "+v"(wd[5]), "+v"(wd[7]));
        uint4v u0 = {wd[0], wd[1], wd[2], wd[3]};
        uint4v u1 = {wd[4], wd[5], wd[6], wd[7]};
        bf16x8 pb0 = __builtin_bit_cast(bf16x8, u0);  // j-slice [j0, j0+16)
        bf16x8 pb1 = __builtin_bit_cast(bf16x8, u1);  // j-slice [j0+16, j0+32)
        accO[0] = mfma32(vf[0][0], pb0, accO[0]);
        accO[0] = mfma32(vf[0][1], pb1, accO[0]);
        accO[1] = mfma32(vf[1][0], pb0, accO[1]);
        accO[1] = mfma32(vf[1][1], pb1, accO[1]);
    }

    // combine j-halves via LDS, then store (jh==0 waves)
    const int il = wi * 32 + l32;
    if (jh == 1) {
#pragma unroll
        for (int db = 0; db < 2; ++db)
#pragma unroll
            for (int r = 0; r < 16; ++r)
                red[il][db * 32 + (r & 3) + 8 * (r >> 2) + 4 * hi] = accO[db][r];
    }
    __syncthreads();
    if (jh == 0) {
#pragma unroll
        for (int db = 0; db < 2; ++db)
#pragma unroll
            for (int r = 0; r < 16; ++r)
                accO[db][r] += red[il][db * 32 + (r & 3) + 8 * (r >> 2) + 4 * hi];
        const int i = i0 + l32;
#pragma unroll
        for (int db = 0; db < 2; ++db)
#pragma unroll
            for (int q = 0; q < 4; ++q) {
                int d = db * 32 + 8 * q + 4 * hi;
                bf16x4 o4;
#pragma unroll
                for (int r = 0; r < 4; ++r) o4[r] = (__bf16)accO[db][4 * q + r];
                *(bf16x4*)&attn_out[(size_t)(b * NN + i) * 1024 + h * 64 + d] = o4;
            }
    }
}

// ---------------- launch ----------------

extern "C" void kernel_launch(void* const* d_in, const int* in_sizes, int n_in,
                              void* d_out, int out_size, void* d_ws, size_t ws_size,
                              hipStream_t stream) {
    (void)in_sizes; (void)n_in; (void)out_size; (void)ws_size;
    const float* x     = (const float*)d_in[0];
    const float* Wq    = (const float*)d_in[1];
    const float* bq    = (const float*)d_in[2];
    const float* Wk    = (const float*)d_in[3];
    const float* bk    = (const float*)d_in[4];
    const float* Wv    = (const float*)d_in[5];
    const float* bv    = (const float*)d_in[6];
    const float* qn_s  = (const float*)d_in[7];
    const float* qn_b  = (const float*)d_in[8];
    const float* kn_s  = (const float*)d_in[9];
    const float* kn_b  = (const float*)d_in[10];
    const float* ib    = (const float*)d_in[11];
    const float* Wo    = (const float*)d_in[12];
    const float* bo    = (const float*)d_in[13];
    const float* gamma = (const float*)d_in[14];
    float* out = (float*)d_out;

    char* ws = (char*)d_ws;
    size_t off = 0;
    auto alloc = [&](size_t bytes) -> void* {
        void* p = ws + off;
        off += (bytes + 255) & ~(size_t)255;
        return p;
    };
    u16* xb       = (u16*)alloc((size_t)4096 * 1024 * 2);   // x bf16
    u16* wqkv_t   = (u16*)alloc((size_t)3072 * 1024 * 2);   // [n][k]
    u16* wo_t     = (u16*)alloc((size_t)1024 * 1024 * 2);
    float* bqkv   = (float*)alloc((size_t)3072 * 4);
    u16* qkv_raw  = (u16*)alloc((size_t)4096 * 3072 * 2);   // q|k|v rows
    u16* Qn       = (u16*)alloc((size_t)32 * 2048 * 64 * 2);
    u16* Kn       = (u16*)alloc((size_t)32 * 2048 * 64 * 2);
    u16* Vtp      = (u16*)alloc((size_t)32 * 64 * 2048 * 2);
    u16* attn_out = (u16*)alloc((size_t)4096 * 1024 * 2);

    k_pack_x<<<4096, 256, 0, stream>>>(x, xb, 1048576);
    k_transpose_w<<<dim3(32, 32, 4), 256, 0, stream>>>(Wq, Wk, Wv, Wo, wqkv_t, wo_t);
    k_pack_bias<<<12, 256, 0, stream>>>(bq, bk, bv, bqkv);
    k_gemm<0><<<dim3(32, 24), 256, 0, stream>>>(xb, wqkv_t, bqkv, nullptr, qkv_raw, 3072);
    k_ln_repack<<<dim3(32, 32), 256, 0, stream>>>(qkv_raw, qn_s, qn_b, kn_s, kn_b, Qn, Kn, Vtp);
    k_attn<<<1024, 256, 0, stream>>>(Qn, Kn, Vtp, ib, attn_out);
    k_gemm<1><<<dim3(32, 8), 256, 0, stream>>>(attn_out, wo_t, bo, gamma, out, 1024);
}